// Round 7
// baseline (490.282 us; speedup 1.0000x reference)
//
#include <hip/hip_runtime.h>
#include <stdint.h>

#define NB 2048
#define OBSD 256
#define POP 10
#define NIN 2560       // OBS_DIM * POP_DIM
#define H 256          // HID1 == HID2
#define OUTP 80        // ACT_DIM * DE_POP
#define TS 25
#define CAP 256        // record slots (fixed halves guarantee <=256 rows per walk)

typedef __attribute__((ext_vector_type(2))) float f2;

// correctly-rounded fp32 exp (fp64 exp then round) — matches SVML high-accuracy
// expf that numpy dispatches to on AVX512 hosts (validated r8: absmax 4.8e-7).
__device__ __forceinline__ float exp_cr(float x) {
    return (float)exp((double)x);
}

__device__ __forceinline__ int rfl(int v) {
    return __builtin_amdgcn_readfirstlane(v);
}

// 25-float accumulator as 12 float2 pairs + 1 scalar (v_pk_fma_f32 path)
struct Acc25 {
    f2 p[12];
    float last;
};

__device__ __forceinline__ void acc_zero(Acc25& a) {
    #pragma unroll
    for (int i = 0; i < 12; ++i) { a.p[i].x = 0.0f; a.p[i].y = 0.0f; }
    a.last = 0.0f;
}

// fold part into acc (per-element RN add == scalar folds), zero part
__device__ __forceinline__ void acc_fold(Acc25& acc, Acc25& part) {
    #pragma unroll
    for (int i = 0; i < 12; ++i) {
        acc.p[i].x = __fadd_rn(acc.p[i].x, part.p[i].x);
        acc.p[i].y = __fadd_rn(acc.p[i].y, part.p[i].y);
        part.p[i].x = 0.0f; part.p[i].y = 0.0f;
    }
    acc.last = __fadd_rn(acc.last, part.last);
    part.last = 0.0f;
}

__device__ __forceinline__ void acc_unpack(const Acc25& a, float* __restrict__ t) {
    #pragma unroll
    for (int i = 0; i < 12; ++i) { t[2 * i] = a.p[i].x; t[2 * i + 1] = a.p[i].y; }
    t[24] = a.last;
}

// packed-byte -> f32 converts (v_cvt_f32_ubyte{0..3}); {0,1} bytes are exact.
__device__ __forceinline__ float ub0(uint32_t v) {
#if __has_builtin(__builtin_amdgcn_cvt_f32_ubyte0)
    return __builtin_amdgcn_cvt_f32_ubyte0(v);
#else
    return (float)(v & 0xffu);
#endif
}
__device__ __forceinline__ float ub1(uint32_t v) {
#if __has_builtin(__builtin_amdgcn_cvt_f32_ubyte1)
    return __builtin_amdgcn_cvt_f32_ubyte1(v);
#else
    return (float)((v >> 8) & 0xffu);
#endif
}
__device__ __forceinline__ float ub2(uint32_t v) {
#if __has_builtin(__builtin_amdgcn_cvt_f32_ubyte2)
    return __builtin_amdgcn_cvt_f32_ubyte2(v);
#else
    return (float)((v >> 16) & 0xffu);
#endif
}
__device__ __forceinline__ float ub3(uint32_t v) {
#if __has_builtin(__builtin_amdgcn_cvt_f32_ubyte3)
    return __builtin_amdgcn_cvt_f32_ubyte3(v);
#else
    return (float)((v >> 24) & 0xffu);
#endif
}

// 25-term fma chain on the 32-B BYTE record: 25 spike bytes {0,1} + 7 pad,
// read as 2 x ds_read_b128 (was 7 LDS ops / 100 B — the r0 kernel is
// LDS-pipe-saturated at CU level: ~850 rows x 18 waves x 52 bank-cyc ~ 95%
// of wall). cvt_f32_ubyte of {0,1} is exactly 0.0f/1.0f, so each fma is
// bitwise == the float-record path (r4 passed with identical absmax; its
// slowness was scratch spill traffic from the windowed skeleton, not this).
__device__ __forceinline__ void fma25b(float w, const uint32_t* __restrict__ rec, Acc25& a) {
    f2 wp; wp.x = w; wp.y = w;
    uint4 q0 = ((const uint4*)rec)[0];
    uint4 q1 = ((const uint4*)rec)[1];
    uint32_t u[7] = {q0.x, q0.y, q0.z, q0.w, q1.x, q1.y, q1.z};
    #pragma unroll
    for (int i = 0; i < 6; ++i) {
        f2 lo, hi;
        lo.x = ub0(u[i]); lo.y = ub1(u[i]);
        hi.x = ub2(u[i]); hi.y = ub3(u[i]);
#if __has_builtin(__builtin_elementwise_fma)
        a.p[2 * i]     = __builtin_elementwise_fma(wp, lo, a.p[2 * i]);
        a.p[2 * i + 1] = __builtin_elementwise_fma(wp, hi, a.p[2 * i + 1]);
#else
        a.p[2 * i].x = fmaf(w, lo.x, a.p[2 * i].x);
        a.p[2 * i].y = fmaf(w, lo.y, a.p[2 * i].y);
        a.p[2 * i + 1].x = fmaf(w, hi.x, a.p[2 * i + 1].x);
        a.p[2 * i + 1].y = fmaf(w, hi.y, a.p[2 * i + 1].y);
#endif
    }
    a.last = fmaf(w, ub0(u[6]), a.last);
}

// spread 4 mask bits into 4 bytes of a u32 (each byte 0 or 1)
__device__ __forceinline__ uint32_t expand4(uint32_t b) {
    return (b & 1u) | ((b & 2u) << 7) | ((b & 4u) << 14) | ((b & 8u) << 21);
}

// write one row record: 25 spike bytes {0,1} + 7 pad = 32 B (2 x uint4 stores)
__device__ __forceinline__ void write_rec(uint32_t* __restrict__ recB, int pos, uint32_t m) {
    uint4 a, c;
    a.x = expand4(m);        a.y = expand4(m >> 4);
    a.z = expand4(m >> 8);   a.w = expand4(m >> 12);
    c.x = expand4(m >> 16);  c.y = expand4(m >> 20);
    c.z = expand4(m >> 24);  c.w = 0u;
    uint4* dst = (uint4*)&recB[pos * 8];
    dst[0] = a; dst[1] = c;
}

// sorted-index event walk, 4-deep register weight prefetch (r0's proven
// shape: 8 live regs, zero spills). Macro form — no reference params (r1's
// reference-select walk spilled an Acc25). DOFOLD is a literal 0/1; TGT is
// the accumulator VARIABLE fma25b targets.
// Uses in-scope: idxL, recB, tid, acc, part, nextB.
#define WALK_BODY(CNT, WT, DOFOLD, TGT)                                        \
  do {                                                                         \
    const int _n = (CNT);                                                      \
    int _pi0 = 0, _pi1 = 0, _pi2 = 0, _pi3 = 0;                                \
    float _pw0 = 0, _pw1 = 0, _pw2 = 0, _pw3 = 0;                              \
    if (_n > 0) { _pi0 = rfl(idxL[0]); _pw0 = (WT)[_pi0 + tid]; }              \
    if (_n > 1) { _pi1 = rfl(idxL[1]); _pw1 = (WT)[_pi1 + tid]; }              \
    if (_n > 2) { _pi2 = rfl(idxL[2]); _pw2 = (WT)[_pi2 + tid]; }              \
    if (_n > 3) { _pi3 = rfl(idxL[3]); _pw3 = (WT)[_pi3 + tid]; }              \
    int _j = 0;                                                                \
    for (; _j + 4 <= _n; _j += 4) {                                            \
      int _c0 = _pi0, _c1 = _pi1, _c2 = _pi2, _c3 = _pi3;                      \
      float _w0 = _pw0, _w1 = _pw1, _w2 = _pw2, _w3 = _pw3;                    \
      if (_j + 4 < _n) { _pi0 = rfl(idxL[_j + 4]); _pw0 = (WT)[_pi0 + tid]; }  \
      if (_j + 5 < _n) { _pi1 = rfl(idxL[_j + 5]); _pw1 = (WT)[_pi1 + tid]; }  \
      if (_j + 6 < _n) { _pi2 = rfl(idxL[_j + 6]); _pw2 = (WT)[_pi2 + tid]; }  \
      if (_j + 7 < _n) { _pi3 = rfl(idxL[_j + 7]); _pw3 = (WT)[_pi3 + tid]; }  \
      if (DOFOLD) { while (_c0 >= nextB) { acc_fold(acc, part); nextB += 320 * H; } } \
      fma25b(_w0, &recB[_j * 8], TGT);                                         \
      if (DOFOLD) { while (_c1 >= nextB) { acc_fold(acc, part); nextB += 320 * H; } } \
      fma25b(_w1, &recB[(_j + 1) * 8], TGT);                                   \
      if (DOFOLD) { while (_c2 >= nextB) { acc_fold(acc, part); nextB += 320 * H; } } \
      fma25b(_w2, &recB[(_j + 2) * 8], TGT);                                   \
      if (DOFOLD) { while (_c3 >= nextB) { acc_fold(acc, part); nextB += 320 * H; } } \
      fma25b(_w3, &recB[(_j + 3) * 8], TGT);                                   \
    }                                                                          \
    for (; _j < _n; ++_j) {           /* remainder (<=3 rows) */               \
      int _ii = rfl(idxL[_j]); float _wv = (WT)[_ii + tid];                    \
      if (DOFOLD) { while (_ii >= nextB) { acc_fold(acc, part); nextB += 320 * H; } } \
      fma25b(_wv, &recB[_j * 8], TGT);                                         \
    }                                                                          \
  } while (0)

// ---------------- K0: COALESCED tiled transposes into fp32 [k][n] layouts ----------------
__global__ __launch_bounds__(256) void k0_transpose(
    const float* __restrict__ w1, const float* __restrict__ w2, const float* __restrict__ w3,
    float* __restrict__ w1t, float* __restrict__ w2t, float* __restrict__ w3t)
{
    __shared__ float tile[32][33];
    int bid = blockIdx.x;
    const float* src; float* dst; int R, C, tr, tc;
    if (bid < 640)      { src = w1; dst = w1t; R = 256; C = NIN; tr = bid / 80; tc = bid % 80; }
    else if (bid < 704) { int t = bid - 640; src = w2; dst = w2t; R = 256; C = 256; tr = t / 8; tc = t % 8; }
    else                { int t = bid - 704; src = w3; dst = w3t; R = OUTP; C = 256; tr = t / 8; tc = t % 8; }
    const int tx = threadIdx.x & 31, ty = threadIdx.x >> 5;
    const int r0 = tr * 32, c0 = tc * 32;
    #pragma unroll
    for (int i = 0; i < 4; ++i) {
        int r = r0 + ty + i * 8, c = c0 + tx;
        if (r < R && c < C) tile[ty + i * 8][tx] = src[r * C + c];
    }
    __syncthreads();
    // dst is [C][R]
    #pragma unroll
    for (int i = 0; i < 4; ++i) {
        int c = c0 + ty + i * 8, r = r0 + tx;
        if (c < C && r < R) dst[c * R + r] = tile[tx][ty + i * 8];
    }
}

// One LIF step, numpy-faithful per-op rounding. vth feeds ONLY the comparison,
// so decide the spike via certified interval from fast fp32 exp (~3 ulp) on a
// division-free argument d*(1/3); margin widened to cover the extra
// ~1.5e-7*|ag| relative arg error. Exact __fdiv_rn + exp_cr fallback only when
// |v - vth_a| <= delta (rare) — decisions provably identical (validated r2-r6).
__device__ __forceinline__ void lif_step(float x, float bv, float& c, float& v, float& s) {
    float cn = __fadd_rn(__fadd_rn(__fmul_rn(c, 0.5f), x), bv);
    c = cn;
    float vp = v;
    float t  = __fmul_rn(__fmul_rn(vp, 0.75f), __fadd_rn(1.0f, -s));
    float vn = __fadd_rn(t, cn);
    float d  = __fadd_rn(vp, -vn);
    v = vn;
    float ag_f  = __fmul_rn(d, 0.33333334f);        // fast approx of d/3
    float ex_a  = __expf(ag_f);                     // fast f32 exp (v_exp_f32)
    float vth_a = 0.25f + 0.5f * (ex_a - 1.0f);
    float delta = (1e-5f + 1e-6f * fabsf(ag_f)) * (ex_a + fabsf(vth_a) + 1.0f);
    if (vn > vth_a + delta) {
        s = 1.0f;
    } else if (vn < vth_a - delta) {
        s = 0.0f;
    } else {                                        // exact fallback (rare)
        float ag  = __fdiv_rn(d, 3.0f);
        float ex  = exp_cr(ag);
        float vth = __fadd_rn(0.25f, __fmul_rn(0.5f, __fadd_rn(ex, -1.0f)));
        s = (vn > vth) ? 1.0f : 0.0f;
    }
}

// ---------------- K1: fused, ONE batch row per block (2048 blocks) ----------------
// Fixed-halves skeleton (spill-clean across r0/r6; the windowed variants
// r1/r2/r4 all demoted state to scratch) + 32-B byte records. LDS ~9.7 KB,
// (256,5): 5 blocks/CU, ~100-reg budget, zero spills expected.
__global__ __launch_bounds__(256, 5) void k1_fused(
    const float* __restrict__ obs, const float* __restrict__ emean, const float* __restrict__ estd,
    const float* __restrict__ w1t, const float* __restrict__ w2t, const float* __restrict__ w3t,
    const float* __restrict__ b1, const float* __restrict__ b2, const float* __restrict__ b3,
    const float* __restrict__ dw, const float* __restrict__ db, float* __restrict__ out)
{
    __shared__ __align__(16) uint32_t recB[CAP * 8];  // 8,192 B byte-records
    __shared__ int   idxL[CAP];                       // 1,024 B premult indices
    __shared__ uint32_t cntA[40];                     //   160 B per-group per-wave counts
    __shared__ uint32_t waveCnt[4];
    __shared__ float cnt3[OUTP];

    const int tid = threadIdx.x;
    const int wave = tid >> 6, lane = tid & 63;
    const int b = blockIdx.x;
    const unsigned long long below = (1ull << lane) - 1ull;

    // ---- Phase A: population encoding, numpy-faithful fp32 op-by-op.
    // Monotonicity screen: arg < -3.23 => a < 0.0396 => 25a(1+eps) < 0.991
    // < 0.999 => mask provably 0 with NO exp call (validated r17). ----
    uint32_t msk[10];
    #pragma unroll
    for (int k = 0; k < 10; ++k) {
        int i = k * 256 + tid;
        int o = i / 10;
        float x  = obs[b * OBSD + o];
        float mu = emean[i];
        float sd = estd[i];
        float dd = __fadd_rn(x, -mu);
        float d2 = __fmul_rn(dd, dd);
        float nm = __fmul_rn(-0.5f, d2);
        float dn = __fmul_rn(sd, sd);
        float arg = __fdiv_rn(nm, dn);
        uint32_t m = 0;
        if (arg >= -3.23f) {
            float a  = exp_cr(arg);
            float volt = 0.0f;
            #pragma unroll
            for (int t = 0; t < TS; ++t) {
                volt = __fadd_rn(volt, a);
                if (volt > 0.999f) { m |= (1u << t); volt = __fadd_rn(volt, -0.999f); }
            }
        }
        msk[k] = m;
    }
    // publish all 10 group counts at once
    #pragma unroll
    for (int k = 0; k < 10; ++k) {
        unsigned long long bal = __ballot(msk[k] != 0u);
        if (lane == 0) cntA[k * 4 + wave] = (uint32_t)__popcll(bal);
    }
    __syncthreads();

    // ---- Phase B: event GEMM1 in two fixed halves (<=256 active rows per
    // half). K-blocks {320 x 8} left-assoc via sorted-index boundary folds;
    // fold boundaries ride on premult idx values — identical FP order. ----
    Acc25 acc, part;
    acc_zero(acc); acc_zero(part);
    int nextB = 320 * H;
    int run = 0;
    #pragma unroll
    for (int k = 0; k < 10; ++k) {
        if (k == 5) {                               // fixed half boundary
            __syncthreads();                        // records complete
            WALK_BODY(run, w1t, 1, part);
            __syncthreads();                        // walk reads done
            run = 0;
        }
        int tot = 0, pre = 0;
        #pragma unroll
        for (int w = 0; w < 4; ++w) {
            int c = (int)cntA[k * 4 + w];
            tot += c;
            if (w < wave) pre += c;
        }
        uint32_t m = msk[k];
        unsigned long long bal = __ballot(m != 0u);
        if (m) {
            int pos = run + pre + (int)__popcll(bal & below);
            idxL[pos] = (k * 256 + tid) * H;
            write_rec(recB, pos, m);
        }
        run += tot;
    }
    __syncthreads();
    WALK_BODY(run, w1t, 1, part);
    acc_fold(acc, part);                            // final fold

    // ---- C1: layer-1 LIF, all 25 steps ----
    uint32_t m1 = 0;
    {
        float cur[TS];
        acc_unpack(acc, cur);
        const float b1v = b1[tid];
        float c1 = 0, v1 = 0, s1 = 0;
        #pragma unroll
        for (int t = 0; t < TS; ++t) {
            lif_step(cur[t], b1v, c1, v1, s1);
            if (s1 != 0.0f) m1 |= (1u << t);
        }
    }
    unsigned long long bal1 = __ballot(m1 != 0u);
    if (lane == 0) waveCnt[wave] = (uint32_t)__popcll(bal1);
    __syncthreads();                                // GEMM1 walk reads done; counts published
    int base1 = 0, n1 = 0;
    #pragma unroll
    for (int w = 0; w < 4; ++w) {
        if (w < wave) base1 += (int)waveCnt[w];
        n1 += (int)waveCnt[w];
    }
    if (m1) {                                       // n1 <= 256: single window
        int pos = base1 + (int)__popcll(bal1 & below);
        idxL[pos] = tid * H;
        write_rec(recB, pos, m1);
    }
    __syncthreads();

    // ---- C2: batched GEMM2 walk (K=256, single window) + layer-2 LIF ----
    Acc25 acc2;
    acc_zero(acc2);
    WALK_BODY(n1, w2t, 0, acc2);
    uint32_t m2 = 0;
    {
        float cur[TS];
        acc_unpack(acc2, cur);
        const float b2v = b2[tid];
        float c2 = 0, v2 = 0, s2 = 0;
        #pragma unroll
        for (int t = 0; t < TS; ++t) {
            lif_step(cur[t], b2v, c2, v2, s2);
            if (s2 != 0.0f) m2 |= (1u << t);
        }
    }
    unsigned long long bal2 = __ballot(m2 != 0u);
    if (lane == 0) waveCnt[wave] = (uint32_t)__popcll(bal2);
    __syncthreads();                                // C2 walk reads done; counts published
    int base2 = 0, n2 = 0;
    #pragma unroll
    for (int w = 0; w < 4; ++w) {
        if (w < wave) base2 += (int)waveCnt[w];
        n2 += (int)waveCnt[w];
    }
    if (m2) {                                       // n2 <= 256: single window
        int pos = base2 + (int)__popcll(bal2 & below);
        idxL[pos] = tid * OUTP;
        write_rec(recB, pos, m2);
    }
    __syncthreads();

    // ---- C3: batched GEMM3 walk + layer-3 LIF (threads 0..79) ----
    if (tid < OUTP) {
        Acc25 x3;
        acc_zero(x3);
        WALK_BODY(n2, w3t, 0, x3);
        float cur[TS];
        acc_unpack(x3, cur);
        const float b3v = b3[tid];
        float c3 = 0, v3 = 0, s3 = 0, ct = 0;
        #pragma unroll
        for (int t = 0; t < TS; ++t) {
            lif_step(cur[t], b3v, c3, v3, s3);
            ct += s3;
        }
        cnt3[tid] = ct;
    }
    __syncthreads();

    // ---- decode: per-op rounding like np einsum (no FMA) ----
    if (tid < 8) {
        float raw = 0.0f;
        #pragma unroll
        for (int pp = 0; pp < POP; ++pp) {
            float po = __fdiv_rn(cnt3[tid * POP + pp], 25.0f);
            raw = __fadd_rn(raw, __fmul_rn(po, dw[tid * POP + pp]));
        }
        raw = __fadd_rn(raw, db[tid]);
        out[b * 8 + tid] = (float)tanh((double)raw);
    }
}

extern "C" void kernel_launch(void* const* d_in, const int* in_sizes, int n_in,
                              void* d_out, int out_size, void* d_ws, size_t ws_size,
                              hipStream_t stream) {
    const float* obs   = (const float*)d_in[0];
    const float* emean = (const float*)d_in[1];
    const float* estd  = (const float*)d_in[2];
    const float* w1    = (const float*)d_in[3];
    const float* b1    = (const float*)d_in[4];
    const float* w2    = (const float*)d_in[5];
    const float* b2    = (const float*)d_in[6];
    const float* w3    = (const float*)d_in[7];
    const float* b3    = (const float*)d_in[8];
    const float* dw    = (const float*)d_in[9];
    const float* db    = (const float*)d_in[10];
    float* out = (float*)d_out;

    char* ws = (char*)d_ws;
    float* w1t = (float*)(ws);                 // 655360 * 4 = 2,621,440 B
    float* w2t = (float*)(ws + 2621440);       //  65536 * 4 =   262,144 B
    float* w3t = (float*)(ws + 2883584);       //  20480 * 4 =    81,920 B

    k0_transpose<<<728, 256, 0, stream>>>(w1, w2, w3, w1t, w2t, w3t);
    k1_fused<<<NB, 256, 0, stream>>>(obs, emean, estd, w1t, w2t, w3t,
                                     b1, b2, b3, dw, db, out);
}

// Round 9
// 451.282 us; speedup vs baseline: 1.0864x; 1.0864x over previous
//
#include <hip/hip_runtime.h>
#include <stdint.h>

#define NB 2048
#define OBSD 256
#define POP 10
#define NIN 2560       // OBS_DIM * POP_DIM
#define H 256          // HID1 == HID2
#define OUTP 80        // ACT_DIM * DE_POP
#define TS 25
#define CAP 256        // record slots (fixed halves guarantee <=256 rows per walk)

typedef __attribute__((ext_vector_type(2))) float f2;

// correctly-rounded fp32 exp (fp64 exp then round) — matches SVML high-accuracy
// expf that numpy dispatches to on AVX512 hosts (validated r8: absmax 4.8e-7).
__device__ __forceinline__ float exp_cr(float x) {
    return (float)exp((double)x);
}

__device__ __forceinline__ int rfl(int v) {
    return __builtin_amdgcn_readfirstlane(v);
}

// 25-float accumulator as 12 float2 pairs + 1 scalar (v_pk_fma_f32 path)
struct Acc25 {
    f2 p[12];
    float last;
};

__device__ __forceinline__ void acc_zero(Acc25& a) {
    #pragma unroll
    for (int i = 0; i < 12; ++i) { a.p[i].x = 0.0f; a.p[i].y = 0.0f; }
    a.last = 0.0f;
}

// fold part into acc (per-element RN add == scalar folds), zero part
__device__ __forceinline__ void acc_fold(Acc25& acc, Acc25& part) {
    #pragma unroll
    for (int i = 0; i < 12; ++i) {
        acc.p[i].x = __fadd_rn(acc.p[i].x, part.p[i].x);
        acc.p[i].y = __fadd_rn(acc.p[i].y, part.p[i].y);
        part.p[i].x = 0.0f; part.p[i].y = 0.0f;
    }
    acc.last = __fadd_rn(acc.last, part.last);
    part.last = 0.0f;
}

__device__ __forceinline__ void acc_unpack(const Acc25& a, float* __restrict__ t) {
    #pragma unroll
    for (int i = 0; i < 12; ++i) { t[2 * i] = a.p[i].x; t[2 * i + 1] = a.p[i].y; }
    t[24] = a.last;
}

// 25-term fma chain on the 24+1 FLOAT record layout: 24 bit-floats in a 96 B
// 16B-aligned block (6 x ds_read_b128, same-address broadcast) + 25th float
// separate. Per-element bitwise == scalar fmaf == BLAS fma(w, s, acc),
// s in {0,1} (validated r12/r16/r17). r4/r7 proved byte-records+cvt shift the
// cost onto VALU issue and regress — float records are the measured optimum.
__device__ __forceinline__ void fma25(float w, const float* __restrict__ rec, float lastv, Acc25& a) {
    f2 wp; wp.x = w; wp.y = w;
    float4 q[6];
    #pragma unroll
    for (int i = 0; i < 6; ++i) q[i] = ((const float4*)rec)[i];
    const f2* r2 = (const f2*)q;   // 12 packed pairs in registers
    #pragma unroll
    for (int i = 0; i < 12; ++i) {
#if __has_builtin(__builtin_elementwise_fma)
        a.p[i] = __builtin_elementwise_fma(wp, r2[i], a.p[i]);
#else
        a.p[i].x = fmaf(w, r2[i].x, a.p[i].x);
        a.p[i].y = fmaf(w, r2[i].y, a.p[i].y);
#endif
    }
    a.last = fmaf(w, lastv, a.last);
}

// write one row record: 24 spike bit-floats (6 float4s) + 25th float separate
__device__ __forceinline__ void write_rec(float* __restrict__ recs, float* __restrict__ rec24,
                                          int pos, uint32_t m) {
    float4* dst = (float4*)&recs[pos * 24];
    #pragma unroll
    for (int p = 0; p < 6; ++p) {
        float4 v;
        v.x = (m >> (4 * p)) & 1u ? 1.0f : 0.0f;
        v.y = (m >> (4 * p + 1)) & 1u ? 1.0f : 0.0f;
        v.z = (m >> (4 * p + 2)) & 1u ? 1.0f : 0.0f;
        v.w = (m >> (4 * p + 3)) & 1u ? 1.0f : 0.0f;
        dst[p] = v;
    }
    rec24[pos] = (m >> 24) & 1u ? 1.0f : 0.0f;
}

// sorted-index event walk, 4-deep register weight prefetch (r0's proven
// shape: 8 live regs, zero spills). Macro form — no reference params (the
// reference-select variant spilled an Acc25). DOFOLD is a literal 0/1; TGT is
// the accumulator VARIABLE fma25 targets.
// Uses in-scope: idxL, recs, rec24, tid, acc, part, nextB.
#define WALK_BODY(CNT, WT, DOFOLD, TGT)                                        \
  do {                                                                         \
    const int _n = (CNT);                                                      \
    int _pi0 = 0, _pi1 = 0, _pi2 = 0, _pi3 = 0;                                \
    float _pw0 = 0, _pw1 = 0, _pw2 = 0, _pw3 = 0;                              \
    if (_n > 0) { _pi0 = rfl(idxL[0]); _pw0 = (WT)[_pi0 + tid]; }              \
    if (_n > 1) { _pi1 = rfl(idxL[1]); _pw1 = (WT)[_pi1 + tid]; }              \
    if (_n > 2) { _pi2 = rfl(idxL[2]); _pw2 = (WT)[_pi2 + tid]; }              \
    if (_n > 3) { _pi3 = rfl(idxL[3]); _pw3 = (WT)[_pi3 + tid]; }              \
    int _j = 0;                                                                \
    for (; _j + 4 <= _n; _j += 4) {                                            \
      int _c0 = _pi0, _c1 = _pi1, _c2 = _pi2, _c3 = _pi3;                      \
      float _w0 = _pw0, _w1 = _pw1, _w2 = _pw2, _w3 = _pw3;                    \
      if (_j + 4 < _n) { _pi0 = rfl(idxL[_j + 4]); _pw0 = (WT)[_pi0 + tid]; }  \
      if (_j + 5 < _n) { _pi1 = rfl(idxL[_j + 5]); _pw1 = (WT)[_pi1 + tid]; }  \
      if (_j + 6 < _n) { _pi2 = rfl(idxL[_j + 6]); _pw2 = (WT)[_pi2 + tid]; }  \
      if (_j + 7 < _n) { _pi3 = rfl(idxL[_j + 7]); _pw3 = (WT)[_pi3 + tid]; }  \
      if (DOFOLD) { while (_c0 >= nextB) { acc_fold(acc, part); nextB += 320 * H; } } \
      fma25(_w0, &recs[_j * 24], rec24[_j], TGT);                              \
      if (DOFOLD) { while (_c1 >= nextB) { acc_fold(acc, part); nextB += 320 * H; } } \
      fma25(_w1, &recs[(_j + 1) * 24], rec24[_j + 1], TGT);                    \
      if (DOFOLD) { while (_c2 >= nextB) { acc_fold(acc, part); nextB += 320 * H; } } \
      fma25(_w2, &recs[(_j + 2) * 24], rec24[_j + 2], TGT);                    \
      if (DOFOLD) { while (_c3 >= nextB) { acc_fold(acc, part); nextB += 320 * H; } } \
      fma25(_w3, &recs[(_j + 3) * 24], rec24[_j + 3], TGT);                    \
    }                                                                          \
    for (; _j < _n; ++_j) {           /* remainder (<=3 rows) */               \
      int _ii = rfl(idxL[_j]); float _wv = (WT)[_ii + tid];                    \
      if (DOFOLD) { while (_ii >= nextB) { acc_fold(acc, part); nextB += 320 * H; } } \
      fma25(_wv, &recs[_j * 24], rec24[_j], TGT);                              \
    }                                                                          \
  } while (0)

// ---------------- K0: COALESCED tiled transposes into fp32 [k][n] layouts ----------------
__global__ __launch_bounds__(256) void k0_transpose(
    const float* __restrict__ w1, const float* __restrict__ w2, const float* __restrict__ w3,
    float* __restrict__ w1t, float* __restrict__ w2t, float* __restrict__ w3t)
{
    __shared__ float tile[32][33];
    int bid = blockIdx.x;
    const float* src; float* dst; int R, C, tr, tc;
    if (bid < 640)      { src = w1; dst = w1t; R = 256; C = NIN; tr = bid / 80; tc = bid % 80; }
    else if (bid < 704) { int t = bid - 640; src = w2; dst = w2t; R = 256; C = 256; tr = t / 8; tc = t % 8; }
    else                { int t = bid - 704; src = w3; dst = w3t; R = OUTP; C = 256; tr = t / 8; tc = t % 8; }
    const int tx = threadIdx.x & 31, ty = threadIdx.x >> 5;
    const int r0 = tr * 32, c0 = tc * 32;
    #pragma unroll
    for (int i = 0; i < 4; ++i) {
        int r = r0 + ty + i * 8, c = c0 + tx;
        if (r < R && c < C) tile[ty + i * 8][tx] = src[r * C + c];
    }
    __syncthreads();
    // dst is [C][R]
    #pragma unroll
    for (int i = 0; i < 4; ++i) {
        int c = c0 + ty + i * 8, r = r0 + tx;
        if (c < C && r < R) dst[c * R + r] = tile[tx][ty + i * 8];
    }
}

// One LIF step, numpy-faithful per-op rounding. vth feeds ONLY the comparison,
// so decide the spike via certified interval from fast fp32 exp (~3 ulp) on a
// division-free argument d*(1/3); margin widened to cover the extra
// ~1.5e-7*|ag| relative arg error. Exact __fdiv_rn + exp_cr fallback only when
// |v - vth_a| <= delta (rare) — decisions provably identical (validated r2-r7).
__device__ __forceinline__ void lif_step(float x, float bv, float& c, float& v, float& s) {
    float cn = __fadd_rn(__fadd_rn(__fmul_rn(c, 0.5f), x), bv);
    c = cn;
    float vp = v;
    float t  = __fmul_rn(__fmul_rn(vp, 0.75f), __fadd_rn(1.0f, -s));
    float vn = __fadd_rn(t, cn);
    float d  = __fadd_rn(vp, -vn);
    v = vn;
    float ag_f  = __fmul_rn(d, 0.33333334f);        // fast approx of d/3
    float ex_a  = __expf(ag_f);                     // fast f32 exp (v_exp_f32)
    float vth_a = 0.25f + 0.5f * (ex_a - 1.0f);
    float delta = (1e-5f + 1e-6f * fabsf(ag_f)) * (ex_a + fabsf(vth_a) + 1.0f);
    if (vn > vth_a + delta) {
        s = 1.0f;
    } else if (vn < vth_a - delta) {
        s = 0.0f;
    } else {                                        // exact fallback (rare)
        float ag  = __fdiv_rn(d, 3.0f);
        float ex  = exp_cr(ag);
        float vth = __fadd_rn(0.25f, __fmul_rn(0.5f, __fadd_rn(ex, -1.0f)));
        s = (vn > vth) ? 1.0f : 0.0f;
    }
}

// ---------------- K1: fused, TWO batch rows per block (1024 blocks) ----------------
// r7's spill-clean skeleton + r0's float-record walk. 1024 blocks = exactly
// 4 blocks/CU in ONE uniform generation (r0's 2048 blocks ran as 5+3 uneven
// generations -> time-avg occupancy sagged to 45%). Inner loop codegen shape
// unchanged from the proven 48-reg form. (r8 bench was an infra failure —
// container acquisition died twice; kernel unmeasured. Resubmitting with the
// first-iteration barrier guarded, otherwise identical.)
__global__ __launch_bounds__(256, 5) void k1_fused(
    const float* __restrict__ obs, const float* __restrict__ emean, const float* __restrict__ estd,
    const float* __restrict__ w1t, const float* __restrict__ w2t, const float* __restrict__ w3t,
    const float* __restrict__ b1, const float* __restrict__ b2, const float* __restrict__ b3,
    const float* __restrict__ dw, const float* __restrict__ db, float* __restrict__ out)
{
    __shared__ __align__(16) float recs[CAP * 24];  // 24,576 B record blocks
    __shared__ float rec24[CAP];                    //  1,024 B 25th floats
    __shared__ int   idxL[CAP];                     //  1,024 B premult indices
    __shared__ uint32_t cntA[40];                   //    160 B per-group per-wave counts
    __shared__ uint32_t waveCnt[4];
    __shared__ float cnt3[OUTP];

    const int tid = threadIdx.x;
    const int wave = tid >> 6, lane = tid & 63;
    const unsigned long long below = (1ull << lane) - 1ull;

    #pragma unroll 1
    for (int rr = 0; rr < 2; ++rr) {
        const int b = (blockIdx.x << 1) | rr;
        if (rr) __syncthreads();                    // prior row's LDS fully retired

        // ---- Phase A: population encoding, numpy-faithful fp32 op-by-op.
        // Monotonicity screen: arg < -3.23 => a < 0.0396 => 25a(1+eps) < 0.991
        // < 0.999 => mask provably 0 with NO exp call (validated r17). ----
        uint32_t msk[10];
        #pragma unroll
        for (int k = 0; k < 10; ++k) {
            int i = k * 256 + tid;
            int o = i / 10;
            float x  = obs[b * OBSD + o];
            float mu = emean[i];
            float sd = estd[i];
            float dd = __fadd_rn(x, -mu);
            float d2 = __fmul_rn(dd, dd);
            float nm = __fmul_rn(-0.5f, d2);
            float dn = __fmul_rn(sd, sd);
            float arg = __fdiv_rn(nm, dn);
            uint32_t m = 0;
            if (arg >= -3.23f) {
                float a  = exp_cr(arg);
                float volt = 0.0f;
                #pragma unroll
                for (int t = 0; t < TS; ++t) {
                    volt = __fadd_rn(volt, a);
                    if (volt > 0.999f) { m |= (1u << t); volt = __fadd_rn(volt, -0.999f); }
                }
            }
            msk[k] = m;
        }
        // publish all 10 group counts at once
        #pragma unroll
        for (int k = 0; k < 10; ++k) {
            unsigned long long bal = __ballot(msk[k] != 0u);
            if (lane == 0) cntA[k * 4 + wave] = (uint32_t)__popcll(bal);
        }
        __syncthreads();

        // ---- Phase B: event GEMM1 in two fixed halves (<=256 active rows per
        // half). K-blocks {320 x 8} left-assoc via sorted-index boundary folds;
        // fold boundaries ride on premult idx values — identical FP order. ----
        Acc25 acc, part;
        acc_zero(acc); acc_zero(part);
        int nextB = 320 * H;
        int run = 0;
        #pragma unroll
        for (int k = 0; k < 10; ++k) {
            if (k == 5) {                           // fixed half boundary
                __syncthreads();                    // records complete
                WALK_BODY(run, w1t, 1, part);
                __syncthreads();                    // walk reads done
                run = 0;
            }
            int tot = 0, pre = 0;
            #pragma unroll
            for (int w = 0; w < 4; ++w) {
                int c = (int)cntA[k * 4 + w];
                tot += c;
                if (w < wave) pre += c;
            }
            uint32_t m = msk[k];
            unsigned long long bal = __ballot(m != 0u);
            if (m) {
                int pos = run + pre + (int)__popcll(bal & below);
                idxL[pos] = (k * 256 + tid) * H;
                write_rec(recs, rec24, pos, m);
            }
            run += tot;
        }
        __syncthreads();
        WALK_BODY(run, w1t, 1, part);
        acc_fold(acc, part);                        // final fold

        // ---- C1: layer-1 LIF, all 25 steps ----
        uint32_t m1 = 0;
        {
            float cur[TS];
            acc_unpack(acc, cur);
            const float b1v = b1[tid];
            float c1 = 0, v1 = 0, s1 = 0;
            #pragma unroll
            for (int t = 0; t < TS; ++t) {
                lif_step(cur[t], b1v, c1, v1, s1);
                if (s1 != 0.0f) m1 |= (1u << t);
            }
        }
        unsigned long long bal1 = __ballot(m1 != 0u);
        if (lane == 0) waveCnt[wave] = (uint32_t)__popcll(bal1);
        __syncthreads();                            // GEMM1 walk reads done; counts published
        int base1 = 0, n1 = 0;
        #pragma unroll
        for (int w = 0; w < 4; ++w) {
            if (w < wave) base1 += (int)waveCnt[w];
            n1 += (int)waveCnt[w];
        }
        if (m1) {                                   // n1 <= 256: single window
            int pos = base1 + (int)__popcll(bal1 & below);
            idxL[pos] = tid * H;
            write_rec(recs, rec24, pos, m1);
        }
        __syncthreads();

        // ---- C2: batched GEMM2 walk (K=256, single window) + layer-2 LIF ----
        Acc25 acc2;
        acc_zero(acc2);
        WALK_BODY(n1, w2t, 0, acc2);
        uint32_t m2 = 0;
        {
            float cur[TS];
            acc_unpack(acc2, cur);
            const float b2v = b2[tid];
            float c2 = 0, v2 = 0, s2 = 0;
            #pragma unroll
            for (int t = 0; t < TS; ++t) {
                lif_step(cur[t], b2v, c2, v2, s2);
                if (s2 != 0.0f) m2 |= (1u << t);
            }
        }
        unsigned long long bal2 = __ballot(m2 != 0u);
        if (lane == 0) waveCnt[wave] = (uint32_t)__popcll(bal2);
        __syncthreads();                            // C2 walk reads done; counts published
        int base2 = 0, n2 = 0;
        #pragma unroll
        for (int w = 0; w < 4; ++w) {
            if (w < wave) base2 += (int)waveCnt[w];
            n2 += (int)waveCnt[w];
        }
        if (m2) {                                   // n2 <= 256: single window
            int pos = base2 + (int)__popcll(bal2 & below);
            idxL[pos] = tid * OUTP;
            write_rec(recs, rec24, pos, m2);
        }
        __syncthreads();

        // ---- C3: batched GEMM3 walk + layer-3 LIF (threads 0..79) ----
        if (tid < OUTP) {
            Acc25 x3;
            acc_zero(x3);
            WALK_BODY(n2, w3t, 0, x3);
            float cur[TS];
            acc_unpack(x3, cur);
            const float b3v = b3[tid];
            float c3 = 0, v3 = 0, s3 = 0, ct = 0;
            #pragma unroll
            for (int t = 0; t < TS; ++t) {
                lif_step(cur[t], b3v, c3, v3, s3);
                ct += s3;
            }
            cnt3[tid] = ct;
        }
        __syncthreads();

        // ---- decode: per-op rounding like np einsum (no FMA) ----
        if (tid < 8) {
            float raw = 0.0f;
            #pragma unroll
            for (int pp = 0; pp < POP; ++pp) {
                float po = __fdiv_rn(cnt3[tid * POP + pp], 25.0f);
                raw = __fadd_rn(raw, __fmul_rn(po, dw[tid * POP + pp]));
            }
            raw = __fadd_rn(raw, db[tid]);
            out[b * 8 + tid] = (float)tanh((double)raw);
        }
    }
}

extern "C" void kernel_launch(void* const* d_in, const int* in_sizes, int n_in,
                              void* d_out, int out_size, void* d_ws, size_t ws_size,
                              hipStream_t stream) {
    const float* obs   = (const float*)d_in[0];
    const float* emean = (const float*)d_in[1];
    const float* estd  = (const float*)d_in[2];
    const float* w1    = (const float*)d_in[3];
    const float* b1    = (const float*)d_in[4];
    const float* w2    = (const float*)d_in[5];
    const float* b2    = (const float*)d_in[6];
    const float* w3    = (const float*)d_in[7];
    const float* b3    = (const float*)d_in[8];
    const float* dw    = (const float*)d_in[9];
    const float* db    = (const float*)d_in[10];
    float* out = (float*)d_out;

    char* ws = (char*)d_ws;
    float* w1t = (float*)(ws);                 // 655360 * 4 = 2,621,440 B
    float* w2t = (float*)(ws + 2621440);       //  65536 * 4 =   262,144 B
    float* w3t = (float*)(ws + 2883584);       //  20480 * 4 =    81,920 B

    k0_transpose<<<728, 256, 0, stream>>>(w1, w2, w3, w1t, w2t, w3t);
    k1_fused<<<1024, 256, 0, stream>>>(obs, emean, estd, w1t, w2t, w3t,
                                       b1, b2, b3, dw, db, out);
}

// Round 10
// 372.539 us; speedup vs baseline: 1.3161x; 1.2114x over previous
//
#include <hip/hip_runtime.h>
#include <stdint.h>

#define NB 2048
#define OBSD 256
#define POP 10
#define NIN 2560       // OBS_DIM * POP_DIM
#define H 256          // HID1 == HID2
#define OUTP 80        // ACT_DIM * DE_POP
#define TS 25
#define CAP 256        // record slots (fixed halves guarantee <=256 rows per walk)

typedef __attribute__((ext_vector_type(2))) float f2;

// correctly-rounded fp32 exp (fp64 exp then round) — matches SVML high-accuracy
// expf that numpy dispatches to on AVX512 hosts (validated r8: absmax 4.8e-7).
__device__ __forceinline__ float exp_cr(float x) {
    return (float)exp((double)x);
}

__device__ __forceinline__ int rfl(int v) {
    return __builtin_amdgcn_readfirstlane(v);
}

// 25-float accumulator as 12 float2 pairs + 1 scalar (v_pk_fma_f32 path)
struct Acc25 {
    f2 p[12];
    float last;
};

__device__ __forceinline__ void acc_zero(Acc25& a) {
    #pragma unroll
    for (int i = 0; i < 12; ++i) { a.p[i].x = 0.0f; a.p[i].y = 0.0f; }
    a.last = 0.0f;
}

// fold part into acc (per-element RN add == scalar folds), zero part
__device__ __forceinline__ void acc_fold(Acc25& acc, Acc25& part) {
    #pragma unroll
    for (int i = 0; i < 12; ++i) {
        acc.p[i].x = __fadd_rn(acc.p[i].x, part.p[i].x);
        acc.p[i].y = __fadd_rn(acc.p[i].y, part.p[i].y);
        part.p[i].x = 0.0f; part.p[i].y = 0.0f;
    }
    acc.last = __fadd_rn(acc.last, part.last);
    part.last = 0.0f;
}

__device__ __forceinline__ void acc_unpack(const Acc25& a, float* __restrict__ t) {
    #pragma unroll
    for (int i = 0; i < 12; ++i) { t[2 * i] = a.p[i].x; t[2 * i + 1] = a.p[i].y; }
    t[24] = a.last;
}

// 25-term fma chain on the 24+1 FLOAT record layout: 24 bit-floats in a 96 B
// 16B-aligned block (6 x ds_read_b128, same-address broadcast) + 25th float
// separate. Per-element bitwise == scalar fmaf == BLAS fma(w, s, acc),
// s in {0,1} (validated r12/r16/r17). r4/r7 proved byte-records+cvt shift the
// cost onto VALU issue and regress — float records are the measured optimum.
__device__ __forceinline__ void fma25(float w, const float* __restrict__ rec, float lastv, Acc25& a) {
    f2 wp; wp.x = w; wp.y = w;
    float4 q[6];
    #pragma unroll
    for (int i = 0; i < 6; ++i) q[i] = ((const float4*)rec)[i];
    const f2* r2 = (const f2*)q;   // 12 packed pairs in registers
    #pragma unroll
    for (int i = 0; i < 12; ++i) {
#if __has_builtin(__builtin_elementwise_fma)
        a.p[i] = __builtin_elementwise_fma(wp, r2[i], a.p[i]);
#else
        a.p[i].x = fmaf(w, r2[i].x, a.p[i].x);
        a.p[i].y = fmaf(w, r2[i].y, a.p[i].y);
#endif
    }
    a.last = fmaf(w, lastv, a.last);
}

// write one row record: 24 spike bit-floats (6 float4s) + 25th float separate
__device__ __forceinline__ void write_rec(float* __restrict__ recs, float* __restrict__ rec24,
                                          int pos, uint32_t m) {
    float4* dst = (float4*)&recs[pos * 24];
    #pragma unroll
    for (int p = 0; p < 6; ++p) {
        float4 v;
        v.x = (m >> (4 * p)) & 1u ? 1.0f : 0.0f;
        v.y = (m >> (4 * p + 1)) & 1u ? 1.0f : 0.0f;
        v.z = (m >> (4 * p + 2)) & 1u ? 1.0f : 0.0f;
        v.w = (m >> (4 * p + 3)) & 1u ? 1.0f : 0.0f;
        dst[p] = v;
    }
    rec24[pos] = (m >> 24) & 1u ? 1.0f : 0.0f;
}

// sorted-index event walk, 4-deep register weight prefetch (r0's proven
// shape: 8 live regs, zero spills; r5's 8-deep spilled). Macro form — no
// reference params (the reference-select variant spilled an Acc25). DOFOLD is
// a literal 0/1; TGT is the accumulator VARIABLE fma25 targets.
// Uses in-scope: idxL, recs, rec24, tid, acc, part, nextB.
#define WALK_BODY(CNT, WT, DOFOLD, TGT)                                        \
  do {                                                                         \
    const int _n = (CNT);                                                      \
    int _pi0 = 0, _pi1 = 0, _pi2 = 0, _pi3 = 0;                                \
    float _pw0 = 0, _pw1 = 0, _pw2 = 0, _pw3 = 0;                              \
    if (_n > 0) { _pi0 = rfl(idxL[0]); _pw0 = (WT)[_pi0 + tid]; }              \
    if (_n > 1) { _pi1 = rfl(idxL[1]); _pw1 = (WT)[_pi1 + tid]; }              \
    if (_n > 2) { _pi2 = rfl(idxL[2]); _pw2 = (WT)[_pi2 + tid]; }              \
    if (_n > 3) { _pi3 = rfl(idxL[3]); _pw3 = (WT)[_pi3 + tid]; }              \
    int _j = 0;                                                                \
    for (; _j + 4 <= _n; _j += 4) {                                            \
      int _c0 = _pi0, _c1 = _pi1, _c2 = _pi2, _c3 = _pi3;                      \
      float _w0 = _pw0, _w1 = _pw1, _w2 = _pw2, _w3 = _pw3;                    \
      if (_j + 4 < _n) { _pi0 = rfl(idxL[_j + 4]); _pw0 = (WT)[_pi0 + tid]; }  \
      if (_j + 5 < _n) { _pi1 = rfl(idxL[_j + 5]); _pw1 = (WT)[_pi1 + tid]; }  \
      if (_j + 6 < _n) { _pi2 = rfl(idxL[_j + 6]); _pw2 = (WT)[_pi2 + tid]; }  \
      if (_j + 7 < _n) { _pi3 = rfl(idxL[_j + 7]); _pw3 = (WT)[_pi3 + tid]; }  \
      if (DOFOLD) { while (_c0 >= nextB) { acc_fold(acc, part); nextB += 320 * H; } } \
      fma25(_w0, &recs[_j * 24], rec24[_j], TGT);                              \
      if (DOFOLD) { while (_c1 >= nextB) { acc_fold(acc, part); nextB += 320 * H; } } \
      fma25(_w1, &recs[(_j + 1) * 24], rec24[_j + 1], TGT);                    \
      if (DOFOLD) { while (_c2 >= nextB) { acc_fold(acc, part); nextB += 320 * H; } } \
      fma25(_w2, &recs[(_j + 2) * 24], rec24[_j + 2], TGT);                    \
      if (DOFOLD) { while (_c3 >= nextB) { acc_fold(acc, part); nextB += 320 * H; } } \
      fma25(_w3, &recs[(_j + 3) * 24], rec24[_j + 3], TGT);                    \
    }                                                                          \
    for (; _j < _n; ++_j) {           /* remainder (<=3 rows) */               \
      int _ii = rfl(idxL[_j]); float _wv = (WT)[_ii + tid];                    \
      if (DOFOLD) { while (_ii >= nextB) { acc_fold(acc, part); nextB += 320 * H; } } \
      fma25(_wv, &recs[_j * 24], rec24[_j], TGT);                              \
    }                                                                          \
  } while (0)

// ---------------- K0: COALESCED tiled transposes into fp32 [k][n] layouts ----------------
__global__ __launch_bounds__(256) void k0_transpose(
    const float* __restrict__ w1, const float* __restrict__ w2, const float* __restrict__ w3,
    float* __restrict__ w1t, float* __restrict__ w2t, float* __restrict__ w3t)
{
    __shared__ float tile[32][33];
    int bid = blockIdx.x;
    const float* src; float* dst; int R, C, tr, tc;
    if (bid < 640)      { src = w1; dst = w1t; R = 256; C = NIN; tr = bid / 80; tc = bid % 80; }
    else if (bid < 704) { int t = bid - 640; src = w2; dst = w2t; R = 256; C = 256; tr = t / 8; tc = t % 8; }
    else                { int t = bid - 704; src = w3; dst = w3t; R = OUTP; C = 256; tr = t / 8; tc = t % 8; }
    const int tx = threadIdx.x & 31, ty = threadIdx.x >> 5;
    const int r0 = tr * 32, c0 = tc * 32;
    #pragma unroll
    for (int i = 0; i < 4; ++i) {
        int r = r0 + ty + i * 8, c = c0 + tx;
        if (r < R && c < C) tile[ty + i * 8][tx] = src[r * C + c];
    }
    __syncthreads();
    // dst is [C][R]
    #pragma unroll
    for (int i = 0; i < 4; ++i) {
        int c = c0 + ty + i * 8, r = r0 + tx;
        if (c < C && r < R) dst[c * R + r] = tile[tx][ty + i * 8];
    }
}

// One LIF step, numpy-faithful per-op rounding. vth feeds ONLY the comparison,
// so decide the spike via certified interval from fast fp32 exp (~3 ulp) on a
// division-free argument d*(1/3); margin widened to cover the extra
// ~1.5e-7*|ag| relative arg error. Exact __fdiv_rn + exp_cr fallback only when
// |v - vth_a| <= delta (rare) — decisions provably identical (validated r2-r9).
__device__ __forceinline__ void lif_step(float x, float bv, float& c, float& v, float& s) {
    float cn = __fadd_rn(__fadd_rn(__fmul_rn(c, 0.5f), x), bv);
    c = cn;
    float vp = v;
    float t  = __fmul_rn(__fmul_rn(vp, 0.75f), __fadd_rn(1.0f, -s));
    float vn = __fadd_rn(t, cn);
    float d  = __fadd_rn(vp, -vn);
    v = vn;
    float ag_f  = __fmul_rn(d, 0.33333334f);        // fast approx of d/3
    float ex_a  = __expf(ag_f);                     // fast f32 exp (v_exp_f32)
    float vth_a = 0.25f + 0.5f * (ex_a - 1.0f);
    float delta = (1e-5f + 1e-6f * fabsf(ag_f)) * (ex_a + fabsf(vth_a) + 1.0f);
    if (vn > vth_a + delta) {
        s = 1.0f;
    } else if (vn < vth_a - delta) {
        s = 0.0f;
    } else {                                        // exact fallback (rare)
        float ag  = __fdiv_rn(d, 3.0f);
        float ex  = exp_cr(ag);
        float vth = __fadd_rn(0.25f, __fmul_rn(0.5f, __fadd_rn(ex, -1.0f)));
        s = (vn > vth) ? 1.0f : 0.0f;
    }
}

// ---------------- K1: fused, ONE batch row per block (2048 blocks) ----------------
// The one unmeasured CLEAN cell: r7's low-barrier skeleton (cntA publish-once
// + fixed halves, ~12 barriers/row vs r0's ~30) x r0's float-record payload
// (the measured-fastest walk). Geometry identical to r0: (256,5), 2048 blocks,
// no row loop (r9 proved the rr-loop wrapper alone re-triggers spills).
__global__ __launch_bounds__(256, 5) void k1_fused(
    const float* __restrict__ obs, const float* __restrict__ emean, const float* __restrict__ estd,
    const float* __restrict__ w1t, const float* __restrict__ w2t, const float* __restrict__ w3t,
    const float* __restrict__ b1, const float* __restrict__ b2, const float* __restrict__ b3,
    const float* __restrict__ dw, const float* __restrict__ db, float* __restrict__ out)
{
    __shared__ __align__(16) float recs[CAP * 24];  // 24,576 B record blocks
    __shared__ float rec24[CAP];                    //  1,024 B 25th floats
    __shared__ int   idxL[CAP];                     //  1,024 B premult indices
    __shared__ uint32_t cntA[40];                   //    160 B per-group per-wave counts
    __shared__ uint32_t waveCnt[4];
    __shared__ float cnt3[OUTP];

    const int tid = threadIdx.x;
    const int wave = tid >> 6, lane = tid & 63;
    const int b = blockIdx.x;
    const unsigned long long below = (1ull << lane) - 1ull;

    // ---- Phase A: population encoding, numpy-faithful fp32 op-by-op.
    // Monotonicity screen: arg < -3.23 => a < 0.0396 => 25a(1+eps) < 0.991
    // < 0.999 => mask provably 0 with NO exp call (validated r17). ----
    uint32_t msk[10];
    #pragma unroll
    for (int k = 0; k < 10; ++k) {
        int i = k * 256 + tid;
        int o = i / 10;
        float x  = obs[b * OBSD + o];
        float mu = emean[i];
        float sd = estd[i];
        float dd = __fadd_rn(x, -mu);
        float d2 = __fmul_rn(dd, dd);
        float nm = __fmul_rn(-0.5f, d2);
        float dn = __fmul_rn(sd, sd);
        float arg = __fdiv_rn(nm, dn);
        uint32_t m = 0;
        if (arg >= -3.23f) {
            float a  = exp_cr(arg);
            float volt = 0.0f;
            #pragma unroll
            for (int t = 0; t < TS; ++t) {
                volt = __fadd_rn(volt, a);
                if (volt > 0.999f) { m |= (1u << t); volt = __fadd_rn(volt, -0.999f); }
            }
        }
        msk[k] = m;
    }
    // publish all 10 group counts at once (saves ~18 barriers vs per-group)
    #pragma unroll
    for (int k = 0; k < 10; ++k) {
        unsigned long long bal = __ballot(msk[k] != 0u);
        if (lane == 0) cntA[k * 4 + wave] = (uint32_t)__popcll(bal);
    }
    __syncthreads();

    // ---- Phase B: event GEMM1 in two fixed halves (<=256 active rows per
    // half). K-blocks {320 x 8} left-assoc via sorted-index boundary folds;
    // fold boundaries ride on premult idx values — identical FP order. ----
    Acc25 acc, part;
    acc_zero(acc); acc_zero(part);
    int nextB = 320 * H;
    int run = 0;
    #pragma unroll
    for (int k = 0; k < 10; ++k) {
        if (k == 5) {                               // fixed half boundary
            __syncthreads();                        // records complete
            WALK_BODY(run, w1t, 1, part);
            __syncthreads();                        // walk reads done
            run = 0;
        }
        int tot = 0, pre = 0;
        #pragma unroll
        for (int w = 0; w < 4; ++w) {
            int c = (int)cntA[k * 4 + w];
            tot += c;
            if (w < wave) pre += c;
        }
        uint32_t m = msk[k];
        unsigned long long bal = __ballot(m != 0u);
        if (m) {
            int pos = run + pre + (int)__popcll(bal & below);
            idxL[pos] = (k * 256 + tid) * H;
            write_rec(recs, rec24, pos, m);
        }
        run += tot;
    }
    __syncthreads();
    WALK_BODY(run, w1t, 1, part);
    acc_fold(acc, part);                            // final fold

    // ---- C1: layer-1 LIF, all 25 steps ----
    uint32_t m1 = 0;
    {
        float cur[TS];
        acc_unpack(acc, cur);
        const float b1v = b1[tid];
        float c1 = 0, v1 = 0, s1 = 0;
        #pragma unroll
        for (int t = 0; t < TS; ++t) {
            lif_step(cur[t], b1v, c1, v1, s1);
            if (s1 != 0.0f) m1 |= (1u << t);
        }
    }
    unsigned long long bal1 = __ballot(m1 != 0u);
    if (lane == 0) waveCnt[wave] = (uint32_t)__popcll(bal1);
    __syncthreads();                                // GEMM1 walk reads done; counts published
    int base1 = 0, n1 = 0;
    #pragma unroll
    for (int w = 0; w < 4; ++w) {
        if (w < wave) base1 += (int)waveCnt[w];
        n1 += (int)waveCnt[w];
    }
    if (m1) {                                       // n1 <= 256: single window
        int pos = base1 + (int)__popcll(bal1 & below);
        idxL[pos] = tid * H;
        write_rec(recs, rec24, pos, m1);
    }
    __syncthreads();

    // ---- C2: batched GEMM2 walk (K=256, single window) + layer-2 LIF ----
    Acc25 acc2;
    acc_zero(acc2);
    WALK_BODY(n1, w2t, 0, acc2);
    uint32_t m2 = 0;
    {
        float cur[TS];
        acc_unpack(acc2, cur);
        const float b2v = b2[tid];
        float c2 = 0, v2 = 0, s2 = 0;
        #pragma unroll
        for (int t = 0; t < TS; ++t) {
            lif_step(cur[t], b2v, c2, v2, s2);
            if (s2 != 0.0f) m2 |= (1u << t);
        }
    }
    unsigned long long bal2 = __ballot(m2 != 0u);
    if (lane == 0) waveCnt[wave] = (uint32_t)__popcll(bal2);
    __syncthreads();                                // C2 walk reads done; counts published
    int base2 = 0, n2 = 0;
    #pragma unroll
    for (int w = 0; w < 4; ++w) {
        if (w < wave) base2 += (int)waveCnt[w];
        n2 += (int)waveCnt[w];
    }
    if (m2) {                                       // n2 <= 256: single window
        int pos = base2 + (int)__popcll(bal2 & below);
        idxL[pos] = tid * OUTP;
        write_rec(recs, rec24, pos, m2);
    }
    __syncthreads();

    // ---- C3: batched GEMM3 walk + layer-3 LIF (threads 0..79) ----
    if (tid < OUTP) {
        Acc25 x3;
        acc_zero(x3);
        WALK_BODY(n2, w3t, 0, x3);
        float cur[TS];
        acc_unpack(x3, cur);
        const float b3v = b3[tid];
        float c3 = 0, v3 = 0, s3 = 0, ct = 0;
        #pragma unroll
        for (int t = 0; t < TS; ++t) {
            lif_step(cur[t], b3v, c3, v3, s3);
            ct += s3;
        }
        cnt3[tid] = ct;
    }
    __syncthreads();

    // ---- decode: per-op rounding like np einsum (no FMA) ----
    if (tid < 8) {
        float raw = 0.0f;
        #pragma unroll
        for (int pp = 0; pp < POP; ++pp) {
            float po = __fdiv_rn(cnt3[tid * POP + pp], 25.0f);
            raw = __fadd_rn(raw, __fmul_rn(po, dw[tid * POP + pp]));
        }
        raw = __fadd_rn(raw, db[tid]);
        out[b * 8 + tid] = (float)tanh((double)raw);
    }
}

extern "C" void kernel_launch(void* const* d_in, const int* in_sizes, int n_in,
                              void* d_out, int out_size, void* d_ws, size_t ws_size,
                              hipStream_t stream) {
    const float* obs   = (const float*)d_in[0];
    const float* emean = (const float*)d_in[1];
    const float* estd  = (const float*)d_in[2];
    const float* w1    = (const float*)d_in[3];
    const float* b1    = (const float*)d_in[4];
    const float* w2    = (const float*)d_in[5];
    const float* b2    = (const float*)d_in[6];
    const float* w3    = (const float*)d_in[7];
    const float* b3    = (const float*)d_in[8];
    const float* dw    = (const float*)d_in[9];
    const float* db    = (const float*)d_in[10];
    float* out = (float*)d_out;

    char* ws = (char*)d_ws;
    float* w1t = (float*)(ws);                 // 655360 * 4 = 2,621,440 B
    float* w2t = (float*)(ws + 2621440);       //  65536 * 4 =   262,144 B
    float* w3t = (float*)(ws + 2883584);       //  20480 * 4 =    81,920 B

    k0_transpose<<<728, 256, 0, stream>>>(w1, w2, w3, w1t, w2t, w3t);
    k1_fused<<<NB, 256, 0, stream>>>(obs, emean, estd, w1t, w2t, w3t,
                                     b1, b2, b3, dw, db, out);
}

// Round 11
// 371.772 us; speedup vs baseline: 1.3188x; 1.0021x over previous
//
#include <hip/hip_runtime.h>
#include <stdint.h>

#define NB 2048
#define OBSD 256
#define POP 10
#define NIN 2560       // OBS_DIM * POP_DIM
#define H 256          // HID1 == HID2
#define OUTP 80        // ACT_DIM * DE_POP
#define TS 25
#define CAP 256        // record slots (fixed halves guarantee <=256 rows per walk)

typedef __attribute__((ext_vector_type(2))) float f2;

// correctly-rounded fp32 exp (fp64 exp then round) — matches SVML high-accuracy
// expf that numpy dispatches to on AVX512 hosts (validated r8: absmax 4.8e-7).
__device__ __forceinline__ float exp_cr(float x) {
    return (float)exp((double)x);
}

__device__ __forceinline__ int rfl(int v) {
    return __builtin_amdgcn_readfirstlane(v);
}

// 25-float accumulator as 12 float2 pairs + 1 scalar (v_pk_fma_f32 path)
struct Acc25 {
    f2 p[12];
    float last;
};

__device__ __forceinline__ void acc_zero(Acc25& a) {
    #pragma unroll
    for (int i = 0; i < 12; ++i) { a.p[i].x = 0.0f; a.p[i].y = 0.0f; }
    a.last = 0.0f;
}

// fold part into acc (per-element RN add == scalar folds), zero part
__device__ __forceinline__ void acc_fold(Acc25& acc, Acc25& part) {
    #pragma unroll
    for (int i = 0; i < 12; ++i) {
        acc.p[i].x = __fadd_rn(acc.p[i].x, part.p[i].x);
        acc.p[i].y = __fadd_rn(acc.p[i].y, part.p[i].y);
        part.p[i].x = 0.0f; part.p[i].y = 0.0f;
    }
    acc.last = __fadd_rn(acc.last, part.last);
    part.last = 0.0f;
}

__device__ __forceinline__ void acc_unpack(const Acc25& a, float* __restrict__ t) {
    #pragma unroll
    for (int i = 0; i < 12; ++i) { t[2 * i] = a.p[i].x; t[2 * i + 1] = a.p[i].y; }
    t[24] = a.last;
}

// 25-term fma chain on the 24+1 FLOAT record layout: 24 bit-floats in a 96 B
// 16B-aligned block (6 x ds_read_b128, same-address broadcast) + 25th float
// separate. Per-element bitwise == scalar fmaf == BLAS fma(w, s, acc),
// s in {0,1} (validated r12/r16/r17). r4/r7 proved byte-records+cvt shift the
// cost onto VALU issue and regress — float records are the measured optimum.
__device__ __forceinline__ void fma25(float w, const float* __restrict__ rec, float lastv, Acc25& a) {
    f2 wp; wp.x = w; wp.y = w;
    float4 q[6];
    #pragma unroll
    for (int i = 0; i < 6; ++i) q[i] = ((const float4*)rec)[i];
    const f2* r2 = (const f2*)q;   // 12 packed pairs in registers
    #pragma unroll
    for (int i = 0; i < 12; ++i) {
#if __has_builtin(__builtin_elementwise_fma)
        a.p[i] = __builtin_elementwise_fma(wp, r2[i], a.p[i]);
#else
        a.p[i].x = fmaf(w, r2[i].x, a.p[i].x);
        a.p[i].y = fmaf(w, r2[i].y, a.p[i].y);
#endif
    }
    a.last = fmaf(w, lastv, a.last);
}

// write one row record: 24 spike bit-floats (6 float4s) + 25th float separate
__device__ __forceinline__ void write_rec(float* __restrict__ recs, float* __restrict__ rec24,
                                          int pos, uint32_t m) {
    float4* dst = (float4*)&recs[pos * 24];
    #pragma unroll
    for (int p = 0; p < 6; ++p) {
        float4 v;
        v.x = (m >> (4 * p)) & 1u ? 1.0f : 0.0f;
        v.y = (m >> (4 * p + 1)) & 1u ? 1.0f : 0.0f;
        v.z = (m >> (4 * p + 2)) & 1u ? 1.0f : 0.0f;
        v.w = (m >> (4 * p + 3)) & 1u ? 1.0f : 0.0f;
        dst[p] = v;
    }
    rec24[pos] = (m >> 24) & 1u ? 1.0f : 0.0f;
}

// sorted-index event walk, 8-WIDE batch with straight 8-deep if-chain
// prefetch — r0/r10's proven idiom (carried regs -> locals -> overwrite),
// widened from 4 to 8 to HALVE latency-exposure points per walk. NOT r5's
// rotating shift-queue (that shape collapsed the allocator to 64 regs and
// spilled). Rows still consumed strictly in sorted order; fold checks still
// fire per-row on idx values before that row's fma -> identical FP order.
// DOFOLD is a literal 0/1; TGT is the accumulator VARIABLE fma25 targets.
// Uses in-scope: idxL, recs, rec24, tid, acc, part, nextB.
#define WALK_BODY(CNT, WT, DOFOLD, TGT)                                        \
  do {                                                                         \
    const int _n = (CNT);                                                      \
    int _pi0 = 0, _pi1 = 0, _pi2 = 0, _pi3 = 0;                                \
    int _pi4 = 0, _pi5 = 0, _pi6 = 0, _pi7 = 0;                                \
    float _pw0 = 0, _pw1 = 0, _pw2 = 0, _pw3 = 0;                              \
    float _pw4 = 0, _pw5 = 0, _pw6 = 0, _pw7 = 0;                              \
    if (_n > 0) { _pi0 = rfl(idxL[0]); _pw0 = (WT)[_pi0 + tid]; }              \
    if (_n > 1) { _pi1 = rfl(idxL[1]); _pw1 = (WT)[_pi1 + tid]; }              \
    if (_n > 2) { _pi2 = rfl(idxL[2]); _pw2 = (WT)[_pi2 + tid]; }              \
    if (_n > 3) { _pi3 = rfl(idxL[3]); _pw3 = (WT)[_pi3 + tid]; }              \
    if (_n > 4) { _pi4 = rfl(idxL[4]); _pw4 = (WT)[_pi4 + tid]; }              \
    if (_n > 5) { _pi5 = rfl(idxL[5]); _pw5 = (WT)[_pi5 + tid]; }              \
    if (_n > 6) { _pi6 = rfl(idxL[6]); _pw6 = (WT)[_pi6 + tid]; }              \
    if (_n > 7) { _pi7 = rfl(idxL[7]); _pw7 = (WT)[_pi7 + tid]; }              \
    int _j = 0;                                                                \
    for (; _j + 8 <= _n; _j += 8) {                                            \
      int _c0 = _pi0, _c1 = _pi1, _c2 = _pi2, _c3 = _pi3;                      \
      int _c4 = _pi4, _c5 = _pi5, _c6 = _pi6, _c7 = _pi7;                      \
      float _w0 = _pw0, _w1 = _pw1, _w2 = _pw2, _w3 = _pw3;                    \
      float _w4 = _pw4, _w5 = _pw5, _w6 = _pw6, _w7 = _pw7;                    \
      if (_j + 8  < _n) { _pi0 = rfl(idxL[_j + 8]);  _pw0 = (WT)[_pi0 + tid]; } \
      if (_j + 9  < _n) { _pi1 = rfl(idxL[_j + 9]);  _pw1 = (WT)[_pi1 + tid]; } \
      if (_j + 10 < _n) { _pi2 = rfl(idxL[_j + 10]); _pw2 = (WT)[_pi2 + tid]; } \
      if (_j + 11 < _n) { _pi3 = rfl(idxL[_j + 11]); _pw3 = (WT)[_pi3 + tid]; } \
      if (_j + 12 < _n) { _pi4 = rfl(idxL[_j + 12]); _pw4 = (WT)[_pi4 + tid]; } \
      if (_j + 13 < _n) { _pi5 = rfl(idxL[_j + 13]); _pw5 = (WT)[_pi5 + tid]; } \
      if (_j + 14 < _n) { _pi6 = rfl(idxL[_j + 14]); _pw6 = (WT)[_pi6 + tid]; } \
      if (_j + 15 < _n) { _pi7 = rfl(idxL[_j + 15]); _pw7 = (WT)[_pi7 + tid]; } \
      if (DOFOLD) { while (_c0 >= nextB) { acc_fold(acc, part); nextB += 320 * H; } } \
      fma25(_w0, &recs[_j * 24], rec24[_j], TGT);                              \
      if (DOFOLD) { while (_c1 >= nextB) { acc_fold(acc, part); nextB += 320 * H; } } \
      fma25(_w1, &recs[(_j + 1) * 24], rec24[_j + 1], TGT);                    \
      if (DOFOLD) { while (_c2 >= nextB) { acc_fold(acc, part); nextB += 320 * H; } } \
      fma25(_w2, &recs[(_j + 2) * 24], rec24[_j + 2], TGT);                    \
      if (DOFOLD) { while (_c3 >= nextB) { acc_fold(acc, part); nextB += 320 * H; } } \
      fma25(_w3, &recs[(_j + 3) * 24], rec24[_j + 3], TGT);                    \
      if (DOFOLD) { while (_c4 >= nextB) { acc_fold(acc, part); nextB += 320 * H; } } \
      fma25(_w4, &recs[(_j + 4) * 24], rec24[_j + 4], TGT);                    \
      if (DOFOLD) { while (_c5 >= nextB) { acc_fold(acc, part); nextB += 320 * H; } } \
      fma25(_w5, &recs[(_j + 5) * 24], rec24[_j + 5], TGT);                    \
      if (DOFOLD) { while (_c6 >= nextB) { acc_fold(acc, part); nextB += 320 * H; } } \
      fma25(_w6, &recs[(_j + 6) * 24], rec24[_j + 6], TGT);                    \
      if (DOFOLD) { while (_c7 >= nextB) { acc_fold(acc, part); nextB += 320 * H; } } \
      fma25(_w7, &recs[(_j + 7) * 24], rec24[_j + 7], TGT);                    \
    }                                                                          \
    for (; _j < _n; ++_j) {           /* remainder (<=7 rows): direct reload */ \
      int _ii = rfl(idxL[_j]); float _wv = (WT)[_ii + tid];                    \
      if (DOFOLD) { while (_ii >= nextB) { acc_fold(acc, part); nextB += 320 * H; } } \
      fma25(_wv, &recs[_j * 24], rec24[_j], TGT);                              \
    }                                                                          \
  } while (0)

// ---------------- K0: COALESCED tiled transposes into fp32 [k][n] layouts ----------------
__global__ __launch_bounds__(256) void k0_transpose(
    const float* __restrict__ w1, const float* __restrict__ w2, const float* __restrict__ w3,
    float* __restrict__ w1t, float* __restrict__ w2t, float* __restrict__ w3t)
{
    __shared__ float tile[32][33];
    int bid = blockIdx.x;
    const float* src; float* dst; int R, C, tr, tc;
    if (bid < 640)      { src = w1; dst = w1t; R = 256; C = NIN; tr = bid / 80; tc = bid % 80; }
    else if (bid < 704) { int t = bid - 640; src = w2; dst = w2t; R = 256; C = 256; tr = t / 8; tc = t % 8; }
    else                { int t = bid - 704; src = w3; dst = w3t; R = OUTP; C = 256; tr = t / 8; tc = t % 8; }
    const int tx = threadIdx.x & 31, ty = threadIdx.x >> 5;
    const int r0 = tr * 32, c0 = tc * 32;
    #pragma unroll
    for (int i = 0; i < 4; ++i) {
        int r = r0 + ty + i * 8, c = c0 + tx;
        if (r < R && c < C) tile[ty + i * 8][tx] = src[r * C + c];
    }
    __syncthreads();
    // dst is [C][R]
    #pragma unroll
    for (int i = 0; i < 4; ++i) {
        int c = c0 + ty + i * 8, r = r0 + tx;
        if (c < C && r < R) dst[c * R + r] = tile[tx][ty + i * 8];
    }
}

// One LIF step, numpy-faithful per-op rounding. vth feeds ONLY the comparison,
// so decide the spike via certified interval from fast fp32 exp (~3 ulp) on a
// division-free argument d*(1/3); margin widened to cover the extra
// ~1.5e-7*|ag| relative arg error. Exact __fdiv_rn + exp_cr fallback only when
// |v - vth_a| <= delta (rare) — decisions provably identical (validated r2-r10).
__device__ __forceinline__ void lif_step(float x, float bv, float& c, float& v, float& s) {
    float cn = __fadd_rn(__fadd_rn(__fmul_rn(c, 0.5f), x), bv);
    c = cn;
    float vp = v;
    float t  = __fmul_rn(__fmul_rn(vp, 0.75f), __fadd_rn(1.0f, -s));
    float vn = __fadd_rn(t, cn);
    float d  = __fadd_rn(vp, -vn);
    v = vn;
    float ag_f  = __fmul_rn(d, 0.33333334f);        // fast approx of d/3
    float ex_a  = __expf(ag_f);                     // fast f32 exp (v_exp_f32)
    float vth_a = 0.25f + 0.5f * (ex_a - 1.0f);
    float delta = (1e-5f + 1e-6f * fabsf(ag_f)) * (ex_a + fabsf(vth_a) + 1.0f);
    if (vn > vth_a + delta) {
        s = 1.0f;
    } else if (vn < vth_a - delta) {
        s = 0.0f;
    } else {                                        // exact fallback (rare)
        float ag  = __fdiv_rn(d, 3.0f);
        float ex  = exp_cr(ag);
        float vth = __fadd_rn(0.25f, __fmul_rn(0.5f, __fadd_rn(ex, -1.0f)));
        s = (vn > vth) ? 1.0f : 0.0f;
    }
}

// ---------------- K1: fused, ONE batch row per block (2048 blocks) ----------------
// r10's winning structure (low-barrier skeleton x float records, 333.5 us)
// with the walk widened to 8-row batches. Geometry unchanged: (256,5),
// 2048 blocks, no row loop (r9: the rr-loop wrapper alone re-triggers spills).
__global__ __launch_bounds__(256, 5) void k1_fused(
    const float* __restrict__ obs, const float* __restrict__ emean, const float* __restrict__ estd,
    const float* __restrict__ w1t, const float* __restrict__ w2t, const float* __restrict__ w3t,
    const float* __restrict__ b1, const float* __restrict__ b2, const float* __restrict__ b3,
    const float* __restrict__ dw, const float* __restrict__ db, float* __restrict__ out)
{
    __shared__ __align__(16) float recs[CAP * 24];  // 24,576 B record blocks
    __shared__ float rec24[CAP];                    //  1,024 B 25th floats
    __shared__ int   idxL[CAP];                     //  1,024 B premult indices
    __shared__ uint32_t cntA[40];                   //    160 B per-group per-wave counts
    __shared__ uint32_t waveCnt[4];
    __shared__ float cnt3[OUTP];

    const int tid = threadIdx.x;
    const int wave = tid >> 6, lane = tid & 63;
    const int b = blockIdx.x;
    const unsigned long long below = (1ull << lane) - 1ull;

    // ---- Phase A: population encoding, numpy-faithful fp32 op-by-op.
    // Monotonicity screen: arg < -3.23 => a < 0.0396 => 25a(1+eps) < 0.991
    // < 0.999 => mask provably 0 with NO exp call (validated r17). ----
    uint32_t msk[10];
    #pragma unroll
    for (int k = 0; k < 10; ++k) {
        int i = k * 256 + tid;
        int o = i / 10;
        float x  = obs[b * OBSD + o];
        float mu = emean[i];
        float sd = estd[i];
        float dd = __fadd_rn(x, -mu);
        float d2 = __fmul_rn(dd, dd);
        float nm = __fmul_rn(-0.5f, d2);
        float dn = __fmul_rn(sd, sd);
        float arg = __fdiv_rn(nm, dn);
        uint32_t m = 0;
        if (arg >= -3.23f) {
            float a  = exp_cr(arg);
            float volt = 0.0f;
            #pragma unroll
            for (int t = 0; t < TS; ++t) {
                volt = __fadd_rn(volt, a);
                if (volt > 0.999f) { m |= (1u << t); volt = __fadd_rn(volt, -0.999f); }
            }
        }
        msk[k] = m;
    }
    // publish all 10 group counts at once (saves ~18 barriers vs per-group)
    #pragma unroll
    for (int k = 0; k < 10; ++k) {
        unsigned long long bal = __ballot(msk[k] != 0u);
        if (lane == 0) cntA[k * 4 + wave] = (uint32_t)__popcll(bal);
    }
    __syncthreads();

    // ---- Phase B: event GEMM1 in two fixed halves (<=256 active rows per
    // half). K-blocks {320 x 8} left-assoc via sorted-index boundary folds;
    // fold boundaries ride on premult idx values — identical FP order. ----
    Acc25 acc, part;
    acc_zero(acc); acc_zero(part);
    int nextB = 320 * H;
    int run = 0;
    #pragma unroll
    for (int k = 0; k < 10; ++k) {
        if (k == 5) {                               // fixed half boundary
            __syncthreads();                        // records complete
            WALK_BODY(run, w1t, 1, part);
            __syncthreads();                        // walk reads done
            run = 0;
        }
        int tot = 0, pre = 0;
        #pragma unroll
        for (int w = 0; w < 4; ++w) {
            int c = (int)cntA[k * 4 + w];
            tot += c;
            if (w < wave) pre += c;
        }
        uint32_t m = msk[k];
        unsigned long long bal = __ballot(m != 0u);
        if (m) {
            int pos = run + pre + (int)__popcll(bal & below);
            idxL[pos] = (k * 256 + tid) * H;
            write_rec(recs, rec24, pos, m);
        }
        run += tot;
    }
    __syncthreads();
    WALK_BODY(run, w1t, 1, part);
    acc_fold(acc, part);                            // final fold

    // ---- C1: layer-1 LIF, all 25 steps ----
    uint32_t m1 = 0;
    {
        float cur[TS];
        acc_unpack(acc, cur);
        const float b1v = b1[tid];
        float c1 = 0, v1 = 0, s1 = 0;
        #pragma unroll
        for (int t = 0; t < TS; ++t) {
            lif_step(cur[t], b1v, c1, v1, s1);
            if (s1 != 0.0f) m1 |= (1u << t);
        }
    }
    unsigned long long bal1 = __ballot(m1 != 0u);
    if (lane == 0) waveCnt[wave] = (uint32_t)__popcll(bal1);
    __syncthreads();                                // GEMM1 walk reads done; counts published
    int base1 = 0, n1 = 0;
    #pragma unroll
    for (int w = 0; w < 4; ++w) {
        if (w < wave) base1 += (int)waveCnt[w];
        n1 += (int)waveCnt[w];
    }
    if (m1) {                                       // n1 <= 256: single window
        int pos = base1 + (int)__popcll(bal1 & below);
        idxL[pos] = tid * H;
        write_rec(recs, rec24, pos, m1);
    }
    __syncthreads();

    // ---- C2: batched GEMM2 walk (K=256, single window) + layer-2 LIF ----
    Acc25 acc2;
    acc_zero(acc2);
    WALK_BODY(n1, w2t, 0, acc2);
    uint32_t m2 = 0;
    {
        float cur[TS];
        acc_unpack(acc2, cur);
        const float b2v = b2[tid];
        float c2 = 0, v2 = 0, s2 = 0;
        #pragma unroll
        for (int t = 0; t < TS; ++t) {
            lif_step(cur[t], b2v, c2, v2, s2);
            if (s2 != 0.0f) m2 |= (1u << t);
        }
    }
    unsigned long long bal2 = __ballot(m2 != 0u);
    if (lane == 0) waveCnt[wave] = (uint32_t)__popcll(bal2);
    __syncthreads();                                // C2 walk reads done; counts published
    int base2 = 0, n2 = 0;
    #pragma unroll
    for (int w = 0; w < 4; ++w) {
        if (w < wave) base2 += (int)waveCnt[w];
        n2 += (int)waveCnt[w];
    }
    if (m2) {                                       // n2 <= 256: single window
        int pos = base2 + (int)__popcll(bal2 & below);
        idxL[pos] = tid * OUTP;
        write_rec(recs, rec24, pos, m2);
    }
    __syncthreads();

    // ---- C3: batched GEMM3 walk + layer-3 LIF (threads 0..79) ----
    if (tid < OUTP) {
        Acc25 x3;
        acc_zero(x3);
        WALK_BODY(n2, w3t, 0, x3);
        float cur[TS];
        acc_unpack(x3, cur);
        const float b3v = b3[tid];
        float c3 = 0, v3 = 0, s3 = 0, ct = 0;
        #pragma unroll
        for (int t = 0; t < TS; ++t) {
            lif_step(cur[t], b3v, c3, v3, s3);
            ct += s3;
        }
        cnt3[tid] = ct;
    }
    __syncthreads();

    // ---- decode: per-op rounding like np einsum (no FMA) ----
    if (tid < 8) {
        float raw = 0.0f;
        #pragma unroll
        for (int pp = 0; pp < POP; ++pp) {
            float po = __fdiv_rn(cnt3[tid * POP + pp], 25.0f);
            raw = __fadd_rn(raw, __fmul_rn(po, dw[tid * POP + pp]));
        }
        raw = __fadd_rn(raw, db[tid]);
        out[b * 8 + tid] = (float)tanh((double)raw);
    }
}

extern "C" void kernel_launch(void* const* d_in, const int* in_sizes, int n_in,
                              void* d_out, int out_size, void* d_ws, size_t ws_size,
                              hipStream_t stream) {
    const float* obs   = (const float*)d_in[0];
    const float* emean = (const float*)d_in[1];
    const float* estd  = (const float*)d_in[2];
    const float* w1    = (const float*)d_in[3];
    const float* b1    = (const float*)d_in[4];
    const float* w2    = (const float*)d_in[5];
    const float* b2    = (const float*)d_in[6];
    const float* w3    = (const float*)d_in[7];
    const float* b3    = (const float*)d_in[8];
    const float* dw    = (const float*)d_in[9];
    const float* db    = (const float*)d_in[10];
    float* out = (float*)d_out;

    char* ws = (char*)d_ws;
    float* w1t = (float*)(ws);                 // 655360 * 4 = 2,621,440 B
    float* w2t = (float*)(ws + 2621440);       //  65536 * 4 =   262,144 B
    float* w3t = (float*)(ws + 2883584);       //  20480 * 4 =    81,920 B

    k0_transpose<<<728, 256, 0, stream>>>(w1, w2, w3, w1t, w2t, w3t);
    k1_fused<<<NB, 256, 0, stream>>>(obs, emean, estd, w1t, w2t, w3t,
                                     b1, b2, b3, dw, db, out);
}